// Round 3
// baseline (20948.232 us; speedup 1.0000x reference)
//
#include <hip/hip_runtime.h>

#define BATCH 65536
#define DIN   256
#define DHID  512
#define BM    64
#define APAD  264   // 256+8 shorts -> 528B row stride, 16B-aligned, 2-way bank alias (free)
#define HPAD  136   // 128+8 shorts -> 272B
#define NSTEPS 8

typedef __attribute__((ext_vector_type(8))) short short8;
typedef __attribute__((ext_vector_type(4))) float f32x4;

__device__ __forceinline__ unsigned short f2bf(float f){
  union { float f; unsigned u; } v; v.f = f;
  unsigned u = v.u;
  unsigned r = (u + 0x7FFFu + ((u >> 16) & 1u)) >> 16;   // RN-even
  return (unsigned short)r;
}
__device__ __forceinline__ float bf2f(unsigned short h){
  union { float f; unsigned u; } v; v.u = ((unsigned)h) << 16; return v.f;
}
__device__ __forceinline__ float tanh_fast(float x){
  float e = __expf(2.0f * x);
  return 1.0f - 2.0f / (e + 1.0f);
}

// W1[256][512] -> W1T hi/lo [512][256]; W2[512][256] -> W2T hi/lo [256][512].
__global__ void prep_weights(const float* __restrict__ W1, const float* __restrict__ W2,
                             unsigned short* __restrict__ W1h, unsigned short* __restrict__ W1l,
                             unsigned short* __restrict__ W2h, unsigned short* __restrict__ W2l){
  int idx = blockIdx.x * blockDim.x + threadIdx.x;
  if (idx >= DIN * DHID) return;
  {
    int k = idx / DHID, n = idx % DHID;
    float v = W1[idx];
    unsigned short h = f2bf(v);
    W1h[n * DIN + k] = h;
    W1l[n * DIN + k] = f2bf(v - bf2f(h));
  }
  {
    int k = idx / DIN, n = idx % DIN;
    float v = W2[idx];
    unsigned short h = f2bf(v);
    W2h[n * DHID + k] = h;
    W2l[n * DHID + k] = f2bf(v - bf2f(h));
  }
}

// One persistent kernel: each block owns 64 rows, integrates through all
// 8 RK4 steps (32 f-evals). State (y, RK4 acc A, stage output F) lives in
// registers in the MFMA C-layout. Requires the 256-VGPR tier:
// __launch_bounds__(512,1) — (512,2) caps at 128 VGPR and spills ~15 GB
// of scratch traffic (round-2 lesson).
__global__ __launch_bounds__(512, 1)
void ode_all(const float* __restrict__ x, float* __restrict__ out,
             const unsigned short* __restrict__ W1h, const unsigned short* __restrict__ W1l,
             const unsigned short* __restrict__ W2h, const unsigned short* __restrict__ W2l,
             const float* __restrict__ b1, const float* __restrict__ b2)
{
  __shared__ unsigned short Ash[BM * APAD];   // 33.8 KB
  __shared__ unsigned short Hsh[BM * HPAD];   // 17.4 KB

  const int tid  = threadIdx.x;
  const int lane = tid & 63;
  const int wid  = tid >> 6;     // 0..7
  const int wr   = wid >> 1;     // 0..3 : 16-row slice
  const int wc   = wid & 1;      // 0..1 : 128-col slice
  const int l15  = lane & 15;
  const int l4   = lane >> 4;    // 0..3
  const size_t r0 = (size_t)blockIdx.x * BM;

  // ---- preload biases into registers ----
  float b1v[4][4];
  #pragma unroll
  for (int ch = 0; ch < 4; ++ch)
    #pragma unroll
    for (int nt = 0; nt < 4; ++nt)
      b1v[ch][nt] = b1[ch * 128 + wc * 64 + nt * 16 + l15];
  float b2v[8];
  #pragma unroll
  for (int nt = 0; nt < 8; ++nt)
    b2v[nt] = b2[wc * 128 + nt * 16 + l15];

  // ---- load y in C-layout: row = wr*16 + l4*4 + r, col = wc*128 + nt*16 + l15 ----
  float y[8][4], A[8][4];
  f32x4 F[8];
  #pragma unroll
  for (int nt = 0; nt < 8; ++nt)
    #pragma unroll
    for (int r = 0; r < 4; ++r)
      y[nt][r] = x[(r0 + wr * 16 + l4 * 4 + r) * DIN + wc * 128 + nt * 16 + l15];

  const float h  = 1.0f / (float)NSTEPS;
  const int arow = wr * 16 + l15;

  for (int s = 0; s < NSTEPS; ++s){
    #pragma unroll 1
    for (int st = 0; st < 4; ++st){
      // ---- stage input X -> Ash (bf16). X: st0:y  st1/2:y+(h/2)F  st3:y+h*F ----
      const float cX = (st == 0) ? 0.0f : (st == 3 ? h : 0.5f * h);
      #pragma unroll
      for (int nt = 0; nt < 8; ++nt){
        #pragma unroll
        for (int r = 0; r < 4; ++r){
          float xv = (st == 0) ? y[nt][r] : y[nt][r] + cX * (F[nt][r] + b2v[nt]);
          Ash[(wr * 16 + l4 * 4 + r) * APAD + wc * 128 + nt * 16 + l15] = f2bf(xv);
        }
      }
      __syncthreads();

      #pragma unroll
      for (int i = 0; i < 8; ++i) F[i] = (f32x4){0.f, 0.f, 0.f, 0.f};

      #pragma unroll 1
      for (int ch = 0; ch < 4; ++ch){
        // ---- GEMM1 chunk: U = X * W1[:, ch*128 + wc*64 .. +64] (2-term: W split) ----
        f32x4 acc1[4];
        #pragma unroll
        for (int i = 0; i < 4; ++i) acc1[i] = (f32x4){0.f, 0.f, 0.f, 0.f};

        #pragma unroll
        for (int ks = 0; ks < 8; ++ks){
          short8 af = *reinterpret_cast<const short8*>(&Ash[arow * APAD + ks * 32 + l4 * 8]);
          #pragma unroll
          for (int nt = 0; nt < 4; ++nt){
            int ncol = ch * 128 + wc * 64 + nt * 16 + l15;
            int boff = ncol * DIN + ks * 32 + l4 * 8;
            short8 bh = *reinterpret_cast<const short8*>(W1h + boff);
            short8 bl = *reinterpret_cast<const short8*>(W1l + boff);
            acc1[nt] = __builtin_amdgcn_mfma_f32_16x16x32_bf16(af, bh, acc1[nt], 0, 0, 0);
            acc1[nt] = __builtin_amdgcn_mfma_f32_16x16x32_bf16(af, bl, acc1[nt], 0, 0, 0);
          }
        }

        __syncthreads();   // previous chunk's Hsh readers done
        // ---- bias + tanh -> H chunk (plain bf16) ----
        #pragma unroll
        for (int nt = 0; nt < 4; ++nt){
          int colL = wc * 64 + nt * 16 + l15;
          #pragma unroll
          for (int r = 0; r < 4; ++r){
            float t = tanh_fast(acc1[nt][r] + b1v[ch][nt]);
            Hsh[(wr * 16 + l4 * 4 + r) * HPAD + colL] = f2bf(t);
          }
        }
        __syncthreads();

        // ---- GEMM2 partial: F += H_chunk * W2[ch*128.. , :] (2-term: W split) ----
        #pragma unroll
        for (int ks = 0; ks < 4; ++ks){
          short8 hf = *reinterpret_cast<const short8*>(&Hsh[arow * HPAD + ks * 32 + l4 * 8]);
          #pragma unroll
          for (int nt = 0; nt < 8; ++nt){
            int ncol = wc * 128 + nt * 16 + l15;
            int boff = ncol * DHID + ch * 128 + ks * 32 + l4 * 8;
            short8 bh = *reinterpret_cast<const short8*>(W2h + boff);
            short8 bl = *reinterpret_cast<const short8*>(W2l + boff);
            F[nt] = __builtin_amdgcn_mfma_f32_16x16x32_bf16(hf, bh, F[nt], 0, 0, 0);
            F[nt] = __builtin_amdgcn_mfma_f32_16x16x32_bf16(hf, bl, F[nt], 0, 0, 0);
          }
        }
      }

      // ---- RK4 state update (F+b2v = k_st) ----
      if (st == 0){
        #pragma unroll
        for (int nt = 0; nt < 8; ++nt)
          #pragma unroll
          for (int r = 0; r < 4; ++r)
            A[nt][r] = y[nt][r] + (h / 6.0f) * (F[nt][r] + b2v[nt]);
      } else if (st == 1 || st == 2){
        #pragma unroll
        for (int nt = 0; nt < 8; ++nt)
          #pragma unroll
          for (int r = 0; r < 4; ++r)
            A[nt][r] += (h / 3.0f) * (F[nt][r] + b2v[nt]);
      } else {
        #pragma unroll
        for (int nt = 0; nt < 8; ++nt)
          #pragma unroll
          for (int r = 0; r < 4; ++r)
            y[nt][r] = A[nt][r] + (h / 6.0f) * (F[nt][r] + b2v[nt]);
      }
    }
  }

  // ---- write final state ----
  #pragma unroll
  for (int nt = 0; nt < 8; ++nt)
    #pragma unroll
    for (int r = 0; r < 4; ++r)
      out[(r0 + wr * 16 + l4 * 4 + r) * DIN + wc * 128 + nt * 16 + l15] = y[nt][r];
}

extern "C" void kernel_launch(void* const* d_in, const int* in_sizes, int n_in,
                              void* d_out, int out_size, void* d_ws, size_t ws_size,
                              hipStream_t stream)
{
  const float* x  = (const float*)d_in[0];
  const float* W1 = (const float*)d_in[1];
  const float* b1 = (const float*)d_in[2];
  const float* W2 = (const float*)d_in[3];
  const float* b2 = (const float*)d_in[4];
  float* out = (float*)d_out;

  unsigned short* W1h = (unsigned short*)d_ws;
  unsigned short* W1l = W1h + DIN * DHID;
  unsigned short* W2h = W1l + DIN * DHID;
  unsigned short* W2l = W2h + DIN * DHID;   // 1 MiB total

  prep_weights<<<512, 256, 0, stream>>>(W1, W2, W1h, W1l, W2h, W2l);
  ode_all<<<BATCH / BM, 512, 0, stream>>>(x, out, W1h, W1l, W2h, W2l, b1, b2);
}

// Round 4
// 9047.075 us; speedup vs baseline: 2.3155x; 2.3155x over previous
//
#include <hip/hip_runtime.h>

#define BATCH 65536
#define DIN   256
#define DHID  512
#define BM    64
#define APAD  264   // 256+8 shorts -> 528B row stride, 16B-aligned
#define HPAD  136   // 128+8 shorts -> 272B
#define NSTEPS 4

typedef __attribute__((ext_vector_type(8))) short short8;
typedef __attribute__((ext_vector_type(4))) float f32x4;

__device__ __forceinline__ unsigned short f2bf(float f){
  union { float f; unsigned u; } v; v.f = f;
  unsigned u = v.u;
  unsigned r = (u + 0x7FFFu + ((u >> 16) & 1u)) >> 16;   // RN-even
  return (unsigned short)r;
}
__device__ __forceinline__ float bf2f(unsigned short h){
  union { float f; unsigned u; } v; v.u = ((unsigned)h) << 16; return v.f;
}
__device__ __forceinline__ float tanh_fast(float x){
  float e = __expf(2.0f * x);
  return 1.0f - 2.0f / (e + 1.0f);
}

// W1[256][512] -> W1T hi/lo [512][256]; W2[512][256] -> W2T hi/lo [256][512].
__global__ void prep_weights(const float* __restrict__ W1, const float* __restrict__ W2,
                             unsigned short* __restrict__ W1h, unsigned short* __restrict__ W1l,
                             unsigned short* __restrict__ W2h, unsigned short* __restrict__ W2l){
  int idx = blockIdx.x * blockDim.x + threadIdx.x;
  if (idx >= DIN * DHID) return;
  {
    int k = idx / DHID, n = idx % DHID;
    float v = W1[idx];
    unsigned short h = f2bf(v);
    W1h[n * DIN + k] = h;
    W1l[n * DIN + k] = f2bf(v - bf2f(h));
  }
  {
    int k = idx / DIN, n = idx % DIN;
    float v = W2[idx];
    unsigned short h = f2bf(v);
    W2h[n * DHID + k] = h;
    W2l[n * DHID + k] = f2bf(v - bf2f(h));
  }
}

// Persistent RK4 integrator. 1024 threads = 16 waves (4 row-groups x 4
// col-groups) per 64-row tile. Per-thread state: y[4][4] + A[4][4] + F[4]
// (f32x4) + acc1[2] + b2v[4] ~ 60 floats -> fits the 128-VGPR tier
// (amdgpu_waves_per_eu(4,4) pins the budget; rounds 2/3 spilled ~15 GB
// at this tier with 512-thread blocks holding 2x the state).
__global__ __launch_bounds__(1024) __attribute__((amdgpu_waves_per_eu(4, 4)))
void ode_all(const float* __restrict__ x, float* __restrict__ out,
             const unsigned short* __restrict__ W1h, const unsigned short* __restrict__ W1l,
             const unsigned short* __restrict__ W2h, const unsigned short* __restrict__ W2l,
             const float* __restrict__ b1, const float* __restrict__ b2)
{
  __shared__ unsigned short Ash[BM * APAD];   // 33.8 KB
  __shared__ unsigned short Hsh[BM * HPAD];   // 17.4 KB

  const int tid  = threadIdx.x;
  const int lane = tid & 63;
  const int wid  = tid >> 6;     // 0..15
  const int wr   = wid >> 2;     // 0..3 : 16-row stripe
  const int wc   = wid & 3;      // 0..3 : 64-col slice of output / 32-col slice of H-chunk
  const int l15  = lane & 15;
  const int l4   = lane >> 4;    // 0..3
  const size_t r0 = (size_t)blockIdx.x * BM;

  // ---- biases for the output columns this thread owns ----
  float b2v[4];
  #pragma unroll
  for (int nt = 0; nt < 4; ++nt)
    b2v[nt] = b2[wc * 64 + nt * 16 + l15];

  // ---- y in C-layout: row = wr*16 + l4*4 + r, col = wc*64 + nt*16 + l15 ----
  float y[4][4], A[4][4];
  f32x4 F[4];
  #pragma unroll
  for (int nt = 0; nt < 4; ++nt)
    #pragma unroll
    for (int r = 0; r < 4; ++r)
      y[nt][r] = x[(r0 + wr * 16 + l4 * 4 + r) * DIN + wc * 64 + nt * 16 + l15];

  const float h  = 1.0f / (float)NSTEPS;
  const int arow = wr * 16 + l15;

  #pragma unroll 1
  for (int s = 0; s < NSTEPS; ++s){
    #pragma unroll 1
    for (int st = 0; st < 4; ++st){
      // ---- stage input X -> Ash (bf16). st0: y; st1/2: y+(h/2)k; st3: y+h*k ----
      const float cX = (st == 3) ? h : 0.5f * h;
      #pragma unroll
      for (int nt = 0; nt < 4; ++nt){
        #pragma unroll
        for (int r = 0; r < 4; ++r){
          float xv = (st == 0) ? y[nt][r]
                               : fmaf(cX, F[nt][r] + b2v[nt], y[nt][r]);
          Ash[(wr * 16 + l4 * 4 + r) * APAD + wc * 64 + nt * 16 + l15] = f2bf(xv);
        }
      }
      __syncthreads();

      #pragma unroll
      for (int i = 0; i < 4; ++i) F[i] = (f32x4){0.f, 0.f, 0.f, 0.f};

      #pragma unroll 1
      for (int ch = 0; ch < 4; ++ch){
        // ---- GEMM1: U = X * W1[:, ch*128 + wc*32 .. +32]  (2-term W split) ----
        f32x4 acc1[2];
        acc1[0] = (f32x4){0.f, 0.f, 0.f, 0.f};
        acc1[1] = (f32x4){0.f, 0.f, 0.f, 0.f};

        #pragma unroll
        for (int ks = 0; ks < 8; ++ks){
          short8 af = *reinterpret_cast<const short8*>(&Ash[arow * APAD + ks * 32 + l4 * 8]);
          #pragma unroll
          for (int nt1 = 0; nt1 < 2; ++nt1){
            int ncol = ch * 128 + wc * 32 + nt1 * 16 + l15;
            int boff = ncol * DIN + ks * 32 + l4 * 8;
            short8 bh = *reinterpret_cast<const short8*>(W1h + boff);
            short8 bl = *reinterpret_cast<const short8*>(W1l + boff);
            acc1[nt1] = __builtin_amdgcn_mfma_f32_16x16x32_bf16(af, bh, acc1[nt1], 0, 0, 0);
            acc1[nt1] = __builtin_amdgcn_mfma_f32_16x16x32_bf16(af, bl, acc1[nt1], 0, 0, 0);
          }
        }

        __syncthreads();   // previous chunk's Hsh readers done
        // ---- bias + tanh -> H chunk (plain bf16) ----
        #pragma unroll
        for (int nt1 = 0; nt1 < 2; ++nt1){
          int colL = wc * 32 + nt1 * 16 + l15;
          float bg = b1[ch * 128 + colL];          // L1-hot global read
          #pragma unroll
          for (int r = 0; r < 4; ++r){
            float t = tanh_fast(acc1[nt1][r] + bg);
            Hsh[(wr * 16 + l4 * 4 + r) * HPAD + colL] = f2bf(t);
          }
        }
        __syncthreads();

        // ---- GEMM2 partial: F += H_chunk * W2[ch*128.. , :] (2-term W split) ----
        #pragma unroll
        for (int ks = 0; ks < 4; ++ks){
          short8 hf = *reinterpret_cast<const short8*>(&Hsh[arow * HPAD + ks * 32 + l4 * 8]);
          #pragma unroll
          for (int nt = 0; nt < 4; ++nt){
            int ncol = wc * 64 + nt * 16 + l15;
            int boff = ncol * DHID + ch * 128 + ks * 32 + l4 * 8;
            short8 bh = *reinterpret_cast<const short8*>(W2h + boff);
            short8 bl = *reinterpret_cast<const short8*>(W2l + boff);
            F[nt] = __builtin_amdgcn_mfma_f32_16x16x32_bf16(hf, bh, F[nt], 0, 0, 0);
            F[nt] = __builtin_amdgcn_mfma_f32_16x16x32_bf16(hf, bl, F[nt], 0, 0, 0);
          }
        }
      }

      // ---- RK4 state update (k_st = F + b2) ----
      if (st == 0){
        #pragma unroll
        for (int nt = 0; nt < 4; ++nt)
          #pragma unroll
          for (int r = 0; r < 4; ++r)
            A[nt][r] = fmaf(h / 6.0f, F[nt][r] + b2v[nt], y[nt][r]);
      } else if (st == 1 || st == 2){
        #pragma unroll
        for (int nt = 0; nt < 4; ++nt)
          #pragma unroll
          for (int r = 0; r < 4; ++r)
            A[nt][r] = fmaf(h / 3.0f, F[nt][r] + b2v[nt], A[nt][r]);
      } else {
        #pragma unroll
        for (int nt = 0; nt < 4; ++nt)
          #pragma unroll
          for (int r = 0; r < 4; ++r)
            y[nt][r] = fmaf(h / 6.0f, F[nt][r] + b2v[nt], A[nt][r]);
      }
    }
  }

  // ---- write final state ----
  #pragma unroll
  for (int nt = 0; nt < 4; ++nt)
    #pragma unroll
    for (int r = 0; r < 4; ++r)
      out[(r0 + wr * 16 + l4 * 4 + r) * DIN + wc * 64 + nt * 16 + l15] = y[nt][r];
}

extern "C" void kernel_launch(void* const* d_in, const int* in_sizes, int n_in,
                              void* d_out, int out_size, void* d_ws, size_t ws_size,
                              hipStream_t stream)
{
  const float* x  = (const float*)d_in[0];
  const float* W1 = (const float*)d_in[1];
  const float* b1 = (const float*)d_in[2];
  const float* W2 = (const float*)d_in[3];
  const float* b2 = (const float*)d_in[4];
  float* out = (float*)d_out;

  unsigned short* W1h = (unsigned short*)d_ws;
  unsigned short* W1l = W1h + DIN * DHID;
  unsigned short* W2h = W1l + DIN * DHID;
  unsigned short* W2l = W2h + DIN * DHID;   // 1 MiB total

  prep_weights<<<512, 256, 0, stream>>>(W1, W2, W1h, W1l, W2h, W2l);
  ode_all<<<BATCH / BM, 1024, 0, stream>>>(x, out, W1h, W1l, W2h, W2l, b1, b2);
}

// Round 5
// 4010.544 us; speedup vs baseline: 5.2233x; 2.2558x over previous
//
#include <hip/hip_runtime.h>

#define BATCH 65536
#define DIN   256
#define DHID  512
#define BM    32
#define APAD  264   // 256+8 shorts -> 528B row stride; b128 window stride 4 mod 32 words (optimal)
#define HPAD  136   // 128+8 shorts -> 272B
#define NSTEPS 4

typedef __attribute__((ext_vector_type(8))) short short8;
typedef __attribute__((ext_vector_type(4))) float f32x4;

__device__ __forceinline__ unsigned short f2bf(float f){
  union { float f; unsigned u; } v; v.f = f;
  unsigned u = v.u;
  unsigned r = (u + 0x7FFFu + ((u >> 16) & 1u)) >> 16;   // RN-even
  return (unsigned short)r;
}
__device__ __forceinline__ float bf2f(unsigned short h){
  union { float f; unsigned u; } v; v.u = ((unsigned)h) << 16; return v.f;
}
__device__ __forceinline__ float tanh_fast(float x){
  float e = __expf(2.0f * x);
  return 1.0f - 2.0f / (e + 1.0f);
}

// W1[256][512] -> W1T hi/lo [512][256]; W2[512][256] -> W2T hi/lo [256][512].
__global__ void prep_weights(const float* __restrict__ W1, const float* __restrict__ W2,
                             unsigned short* __restrict__ W1h, unsigned short* __restrict__ W1l,
                             unsigned short* __restrict__ W2h, unsigned short* __restrict__ W2l){
  int idx = blockIdx.x * blockDim.x + threadIdx.x;
  if (idx >= DIN * DHID) return;
  {
    int k = idx / DHID, n = idx % DHID;
    float v = W1[idx];
    unsigned short h = f2bf(v);
    W1h[n * DIN + k] = h;
    W1l[n * DIN + k] = f2bf(v - bf2f(h));
  }
  {
    int k = idx / DIN, n = idx % DIN;
    float v = W2[idx];
    unsigned short h = f2bf(v);
    W2h[n * DHID + k] = h;
    W2l[n * DHID + k] = f2bf(v - bf2f(h));
  }
}

// Persistent RK4 integrator. BM=32 rows/block, 512 threads = 8 waves; each
// wave owns 32 rows x 32 cols as 2x2 16x16 MFMA tiles (each weight fragment
// feeds 2 row-tile MFMAs -> half the L2 B-traffic per FLOP). Per-thread
// persistent state: y[2][2][4] + A + F + b2v = 50 floats, ~86 peak -> fits
// the 128-VGPR allocation that 512-thread blocks get naturally (rounds 2-4
// lesson: exceed it and the allocator spills GBs to scratch rather than
// raising VGPR count).
__global__ __launch_bounds__(512, 2)
void ode_all(const float* __restrict__ x, float* __restrict__ out,
             const unsigned short* __restrict__ W1h, const unsigned short* __restrict__ W1l,
             const unsigned short* __restrict__ W2h, const unsigned short* __restrict__ W2l,
             const float* __restrict__ b1, const float* __restrict__ b2)
{
  __shared__ unsigned short Ash[BM * APAD];   // 16.9 KB
  __shared__ unsigned short Hsh[BM * HPAD];   // 8.7 KB

  const int tid  = threadIdx.x;
  const int lane = tid & 63;
  const int wid  = tid >> 6;     // 0..7 : 32-col slice of output / 16-col slice of H chunk
  const int l15  = lane & 15;
  const int l4   = lane >> 4;    // 0..3
  const size_t r0 = (size_t)blockIdx.x * BM;

  float b2v[2];
  #pragma unroll
  for (int nt = 0; nt < 2; ++nt)
    b2v[nt] = b2[wid * 32 + nt * 16 + l15];

  // C-layout: row = rt*16 + l4*4 + r, col = wid*32 + nt*16 + l15
  float y[2][2][4], A[2][2][4];
  f32x4 F[2][2];
  #pragma unroll
  for (int rt = 0; rt < 2; ++rt)
    #pragma unroll
    for (int nt = 0; nt < 2; ++nt)
      #pragma unroll
      for (int r = 0; r < 4; ++r)
        y[rt][nt][r] = x[(r0 + rt * 16 + l4 * 4 + r) * DIN + wid * 32 + nt * 16 + l15];

  const float h = 1.0f / (float)NSTEPS;

  #pragma unroll 1
  for (int s = 0; s < NSTEPS; ++s){
    #pragma unroll 1
    for (int st = 0; st < 4; ++st){
      // ---- stage input X -> Ash (bf16). st0: y; st1/2: y+(h/2)k; st3: y+h*k ----
      const float cX = (st == 3) ? h : 0.5f * h;
      #pragma unroll
      for (int rt = 0; rt < 2; ++rt)
        #pragma unroll
        for (int nt = 0; nt < 2; ++nt)
          #pragma unroll
          for (int r = 0; r < 4; ++r){
            float xv = (st == 0) ? y[rt][nt][r]
                                 : fmaf(cX, F[rt][nt][r] + b2v[nt], y[rt][nt][r]);
            Ash[(rt * 16 + l4 * 4 + r) * APAD + wid * 32 + nt * 16 + l15] = f2bf(xv);
          }
      __syncthreads();

      #pragma unroll
      for (int i = 0; i < 2; ++i)
        #pragma unroll
        for (int j = 0; j < 2; ++j)
          F[i][j] = (f32x4){0.f, 0.f, 0.f, 0.f};

      #pragma unroll 1
      for (int ch = 0; ch < 4; ++ch){
        // ---- GEMM1: U = X * W1[:, ch*128 + wid*16 .. +16]  (2-term W split) ----
        f32x4 acc1[2];
        acc1[0] = (f32x4){0.f, 0.f, 0.f, 0.f};
        acc1[1] = (f32x4){0.f, 0.f, 0.f, 0.f};

        #pragma unroll
        for (int ks = 0; ks < 8; ++ks){
          short8 af0 = *reinterpret_cast<const short8*>(&Ash[(     l15) * APAD + ks * 32 + l4 * 8]);
          short8 af1 = *reinterpret_cast<const short8*>(&Ash[(16 + l15) * APAD + ks * 32 + l4 * 8]);
          int ncol = ch * 128 + wid * 16 + l15;
          int boff = ncol * DIN + ks * 32 + l4 * 8;
          short8 bh = *reinterpret_cast<const short8*>(W1h + boff);
          short8 bl = *reinterpret_cast<const short8*>(W1l + boff);
          acc1[0] = __builtin_amdgcn_mfma_f32_16x16x32_bf16(af0, bh, acc1[0], 0, 0, 0);
          acc1[0] = __builtin_amdgcn_mfma_f32_16x16x32_bf16(af0, bl, acc1[0], 0, 0, 0);
          acc1[1] = __builtin_amdgcn_mfma_f32_16x16x32_bf16(af1, bh, acc1[1], 0, 0, 0);
          acc1[1] = __builtin_amdgcn_mfma_f32_16x16x32_bf16(af1, bl, acc1[1], 0, 0, 0);
        }

        __syncthreads();   // previous chunk's Hsh readers done
        // ---- bias + tanh -> H chunk (plain bf16), 16 cols per wave ----
        {
          float bg = b1[ch * 128 + wid * 16 + l15];
          #pragma unroll
          for (int rt = 0; rt < 2; ++rt)
            #pragma unroll
            for (int r = 0; r < 4; ++r){
              float t = tanh_fast(acc1[rt][r] + bg);
              Hsh[(rt * 16 + l4 * 4 + r) * HPAD + wid * 16 + l15] = f2bf(t);
            }
        }
        __syncthreads();

        // ---- GEMM2 partial: F += H_chunk * W2[ch*128.. , :] (2-term W split) ----
        #pragma unroll
        for (int ks = 0; ks < 4; ++ks){
          short8 hf0 = *reinterpret_cast<const short8*>(&Hsh[(     l15) * HPAD + ks * 32 + l4 * 8]);
          short8 hf1 = *reinterpret_cast<const short8*>(&Hsh[(16 + l15) * HPAD + ks * 32 + l4 * 8]);
          #pragma unroll
          for (int nt = 0; nt < 2; ++nt){
            int ncol = wid * 32 + nt * 16 + l15;
            int boff = ncol * DHID + ch * 128 + ks * 32 + l4 * 8;
            short8 bh = *reinterpret_cast<const short8*>(W2h + boff);
            short8 bl = *reinterpret_cast<const short8*>(W2l + boff);
            F[0][nt] = __builtin_amdgcn_mfma_f32_16x16x32_bf16(hf0, bh, F[0][nt], 0, 0, 0);
            F[0][nt] = __builtin_amdgcn_mfma_f32_16x16x32_bf16(hf0, bl, F[0][nt], 0, 0, 0);
            F[1][nt] = __builtin_amdgcn_mfma_f32_16x16x32_bf16(hf1, bh, F[1][nt], 0, 0, 0);
            F[1][nt] = __builtin_amdgcn_mfma_f32_16x16x32_bf16(hf1, bl, F[1][nt], 0, 0, 0);
          }
        }
      }

      // ---- RK4 state update (k_st = F + b2) ----
      if (st == 0){
        #pragma unroll
        for (int rt = 0; rt < 2; ++rt)
          #pragma unroll
          for (int nt = 0; nt < 2; ++nt)
            #pragma unroll
            for (int r = 0; r < 4; ++r)
              A[rt][nt][r] = fmaf(h / 6.0f, F[rt][nt][r] + b2v[nt], y[rt][nt][r]);
      } else if (st == 1 || st == 2){
        #pragma unroll
        for (int rt = 0; rt < 2; ++rt)
          #pragma unroll
          for (int nt = 0; nt < 2; ++nt)
            #pragma unroll
            for (int r = 0; r < 4; ++r)
              A[rt][nt][r] = fmaf(h / 3.0f, F[rt][nt][r] + b2v[nt], A[rt][nt][r]);
      } else {
        #pragma unroll
        for (int rt = 0; rt < 2; ++rt)
          #pragma unroll
          for (int nt = 0; nt < 2; ++nt)
            #pragma unroll
            for (int r = 0; r < 4; ++r)
              y[rt][nt][r] = fmaf(h / 6.0f, F[rt][nt][r] + b2v[nt], A[rt][nt][r]);
      }
    }
  }

  // ---- write final state ----
  #pragma unroll
  for (int rt = 0; rt < 2; ++rt)
    #pragma unroll
    for (int nt = 0; nt < 2; ++nt)
      #pragma unroll
      for (int r = 0; r < 4; ++r)
        out[(r0 + rt * 16 + l4 * 4 + r) * DIN + wid * 32 + nt * 16 + l15] = y[rt][nt][r];
}

extern "C" void kernel_launch(void* const* d_in, const int* in_sizes, int n_in,
                              void* d_out, int out_size, void* d_ws, size_t ws_size,
                              hipStream_t stream)
{
  const float* x  = (const float*)d_in[0];
  const float* W1 = (const float*)d_in[1];
  const float* b1 = (const float*)d_in[2];
  const float* W2 = (const float*)d_in[3];
  const float* b2 = (const float*)d_in[4];
  float* out = (float*)d_out;

  unsigned short* W1h = (unsigned short*)d_ws;
  unsigned short* W1l = W1h + DIN * DHID;
  unsigned short* W2h = W1l + DIN * DHID;
  unsigned short* W2l = W2h + DIN * DHID;   // 1 MiB total

  prep_weights<<<512, 256, 0, stream>>>(W1, W2, W1h, W1l, W2h, W2l);
  ode_all<<<BATCH / BM, 512, 0, stream>>>(x, out, W1h, W1l, W2h, W2l, b1, b2);
}